// Round 5
// baseline (2816.053 us; speedup 1.0000x reference)
//
#include <hip/hip_runtime.h>
#include <math.h>

#define N1 1024
#define NN2 (N1*N1)
#define LL 16384

// ---------------- elementwise ----------------
__global__ __launch_bounds__(256) void k_scale(const float* __restrict__ A,
                                               const float* __restrict__ logd,
                                               float* __restrict__ e) {
    int i = blockIdx.x * 256 + threadIdx.x;
    float d = expf(logd[0]);
    e[i] = 0.5f * d * A[i];
}

__global__ __launch_bounds__(256) void k_add(const float* __restrict__ a,
                                             const float* __restrict__ b,
                                             float* __restrict__ o) {
    int i = blockIdx.x * 256 + threadIdx.x;
    o[i] = a[i] + b[i];
}

// ---------------- chain-partial device code (mode 0 = Q rows, 1 = P cols) --------
__device__ __forceinline__ void chain_part(const float* __restrict__ M,
                                           float* __restrict__ V,
                                           float* __restrict__ CP,
                                           int w, int lkc, int mode, int cb,
                                           float* sV, float (*red)[64]) {
    int kc = 1 << lkc;
    int i = cb >> (4 + lkc);
    int ky = (cb >> 4) & (kc - 1);
    int nx = cb & 15;
    int mlen = N1 >> lkc;
    int m0 = ky * mlen, n0 = nx * 64;
    int t = threadIdx.x;
    const float* Vi = V + (size_t)i * N1 + m0;
    if (t * 4 < mlen) *(float4*)&sV[t * 4] = *(const float4*)&Vi[t * 4];
    __syncthreads();
    int wave = t >> 6, lane = t & 63;
    if (mode == 0) {
        for (int rr = 0; rr < 16; ++rr) {
            int n = n0 + wave * 16 + rr;
            const float* Mr = M + (size_t)n * N1 + m0;
            float acc = 0.f;
            for (int m = lane * 4; m < mlen; m += 256) {
                float4 a = *(const float4*)&Mr[m];
                float4 v = *(const float4*)&sV[m];
                acc += a.x * v.x + a.y * v.y + a.z * v.z + a.w * v.w;
            }
#pragma unroll
            for (int off = 32; off > 0; off >>= 1) acc += __shfl_down(acc, off, 64);
            if (lane == 0) {
                if (kc == 1) V[(size_t)(w + i) * N1 + n] = sV[n] + acc;
                else CP[((size_t)i * kc + ky) * N1 + n] = acc;
            }
        }
    } else {
        int n = n0 + lane;
        int msub = mlen >> 2;
        int mb = wave * msub;
        float acc = 0.f;
#pragma unroll 8
        for (int m = 0; m < msub; ++m)
            acc += sV[mb + m] * M[(size_t)(m0 + mb + m) * N1 + n];
        red[wave][lane] = acc;
        __syncthreads();
        if (t < 64) {
            float s = red[0][t] + red[1][t] + red[2][t] + red[3][t];
            if (kc == 1) V[(size_t)(w + i) * N1 + n0 + t] = sV[n0 + t] + s;
            else CP[((size_t)i * kc + ky) * N1 + n0 + t] = s;
        }
    }
}

// ---------------- fused dispatch: [chain blocks | 256 SGEMM split-K blocks] --------
// GEMM: part[z] = Ain[:, z*256:(z+1)*256] @ Bin[z*256:..., :]
// 128x128 tile, BK=16, 256 threads, 8x8/thread (split 4+4), double-buffered LDS.
__global__ __launch_bounds__(256, 2) void k_fused(const float* __restrict__ Ain,
                                                  const float* __restrict__ Bin,
                                                  float* __restrict__ part,
                                                  float* __restrict__ V,
                                                  float* __restrict__ CP,
                                                  int w, int lkc, int nchain, int mode) {
    __shared__ float As[2][16][136];
    __shared__ float Bs[2][16][136];
    __shared__ float sV[N1];
    __shared__ float red[4][64];
    int b = blockIdx.x;
    if (b < nchain) {
        chain_part(Ain, V, CP, w, lkc, mode, b, sV, red);
        return;
    }
    int g = b - nchain;
    int t = threadIdx.x;
    int z = g >> 6, ty = (g >> 3) & 7, tx = g & 7;
    int m0 = ty * 128, n0 = tx * 128, kz = z * 256;
    int tm = (t & 15) * 4, tn = (t >> 4) * 4;
    int arow = t >> 1, akb = (t & 1) * 8;
    int bkr = t >> 4, bnb = (t & 15) * 8;
    const float* Ap = Ain + (size_t)(m0 + arow) * N1 + kz + akb;
    const float* Bp = Bin + (size_t)(kz + bkr) * N1 + n0 + bnb;

    float4 pa0 = *(const float4*)(Ap);
    float4 pa1 = *(const float4*)(Ap + 4);
    float4 pb0 = *(const float4*)(Bp);
    float4 pb1 = *(const float4*)(Bp + 4);
    As[0][akb + 0][arow] = pa0.x; As[0][akb + 1][arow] = pa0.y;
    As[0][akb + 2][arow] = pa0.z; As[0][akb + 3][arow] = pa0.w;
    As[0][akb + 4][arow] = pa1.x; As[0][akb + 5][arow] = pa1.y;
    As[0][akb + 6][arow] = pa1.z; As[0][akb + 7][arow] = pa1.w;
    *(float4*)&Bs[0][bkr][bnb]     = pb0;
    *(float4*)&Bs[0][bkr][bnb + 4] = pb1;
    __syncthreads();

    float acc[8][8];
#pragma unroll
    for (int i = 0; i < 8; ++i)
#pragma unroll
        for (int j = 0; j < 8; ++j) acc[i][j] = 0.f;

    for (int tt_ = 0; tt_ < 16; ++tt_) {
        int cb = tt_ & 1;
        float4 na0, na1, nb0, nb1;
        if (tt_ < 15) {
            int k0 = (tt_ + 1) * 16;
            na0 = *(const float4*)(Ap + k0);
            na1 = *(const float4*)(Ap + k0 + 4);
            nb0 = *(const float4*)(Bp + (size_t)k0 * N1);
            nb1 = *(const float4*)(Bp + (size_t)k0 * N1 + 4);
        }
#pragma unroll
        for (int k = 0; k < 16; ++k) {
            float4 a0 = *(float4*)&As[cb][k][tm];
            float4 a1 = *(float4*)&As[cb][k][tm + 64];
            float4 b0 = *(float4*)&Bs[cb][k][tn];
            float4 b1 = *(float4*)&Bs[cb][k][tn + 64];
            float av[8] = {a0.x, a0.y, a0.z, a0.w, a1.x, a1.y, a1.z, a1.w};
            float bv[8] = {b0.x, b0.y, b0.z, b0.w, b1.x, b1.y, b1.z, b1.w};
#pragma unroll
            for (int i = 0; i < 8; ++i)
#pragma unroll
                for (int j = 0; j < 8; ++j) acc[i][j] += av[i] * bv[j];
        }
        if (tt_ < 15) {
            int nb_ = cb ^ 1;
            As[nb_][akb + 0][arow] = na0.x; As[nb_][akb + 1][arow] = na0.y;
            As[nb_][akb + 2][arow] = na0.z; As[nb_][akb + 3][arow] = na0.w;
            As[nb_][akb + 4][arow] = na1.x; As[nb_][akb + 5][arow] = na1.y;
            As[nb_][akb + 6][arow] = na1.z; As[nb_][akb + 7][arow] = na1.w;
            *(float4*)&Bs[nb_][bkr][bnb]     = nb0;
            *(float4*)&Bs[nb_][bkr][bnb + 4] = nb1;
            __syncthreads();
        }
    }
    float* Po = part + (size_t)z * NN2;
#pragma unroll
    for (int ih = 0; ih < 2; ++ih)
#pragma unroll
        for (int i = 0; i < 4; ++i) {
            int row = m0 + tm + ih * 64 + i;
            float4 o0 = {acc[ih * 4 + i][0], acc[ih * 4 + i][1], acc[ih * 4 + i][2], acc[ih * 4 + i][3]};
            float4 o1 = {acc[ih * 4 + i][4], acc[ih * 4 + i][5], acc[ih * 4 + i][6], acc[ih * 4 + i][7]};
            *(float4*)&Po[(size_t)row * N1 + n0 + tn] = o0;
            *(float4*)&Po[(size_t)row * N1 + n0 + tn + 64] = o1;
        }
}

// ---------------- chain-partial-only dispatch ----------------
__global__ __launch_bounds__(256) void k_cpart(const float* __restrict__ M,
                                               float* __restrict__ V,
                                               float* __restrict__ CP,
                                               int w, int lkc, int mode) {
    __shared__ float sV[N1];
    __shared__ float red[4][64];
    chain_part(M, V, CP, w, lkc, mode, blockIdx.x, sV, red);
}

// ---------------- fused reduce: [1024 mmred blocks | 4w chainR blocks] ------------
__global__ __launch_bounds__(256) void k_redu(const float* __restrict__ part,
                                              const float* __restrict__ Aadd,
                                              float* __restrict__ C,
                                              float alpha, float beta,
                                              float* __restrict__ V,
                                              const float* __restrict__ CP,
                                              int w, int kc) {
    int b = blockIdx.x, t = threadIdx.x;
    if (b < 1024) {
        int i = (b * 256 + t) * 4;
        float4 p0 = *(const float4*)&part[i];
        float4 p1 = *(const float4*)&part[NN2 + i];
        float4 p2 = *(const float4*)&part[2 * (size_t)NN2 + i];
        float4 p3 = *(const float4*)&part[3 * (size_t)NN2 + i];
        float4 av = *(const float4*)&Aadd[i];
        float4 o;
        o.x = alpha * ((p0.x + p1.x) + (p2.x + p3.x)) + beta * av.x;
        o.y = alpha * ((p0.y + p1.y) + (p2.y + p3.y)) + beta * av.y;
        o.z = alpha * ((p0.z + p1.z) + (p2.z + p3.z)) + beta * av.z;
        o.w = alpha * ((p0.w + p1.w) + (p2.w + p3.w)) + beta * av.w;
        *(float4*)&C[i] = o;
    } else {
        int rb = b - 1024;
        int i = rb >> 2;
        int n = (rb & 3) * 256 + t;
        const float* pp = CP + (size_t)i * kc * N1 + n;
        float s = 0.f;
        for (int c = 0; c < kc; ++c) s += pp[(size_t)c * N1];
        V[(size_t)(w + i) * N1 + n] = V[(size_t)i * N1 + n] + s;
    }
}

// ---------------- init reduce: Q[0] = d*(B + 0.5*D1@B); P[0] = C ----------------
__global__ __launch_bounds__(256) void k_initR(const float* __restrict__ Bv,
                                               const float* __restrict__ Cv,
                                               const float* __restrict__ logd,
                                               const float* __restrict__ part,
                                               float* __restrict__ Q,
                                               float* __restrict__ P) {
    int n = blockIdx.x * 256 + threadIdx.x;
    float s = 0.f;
    for (int c = 0; c < 16; ++c) s += part[(size_t)c * N1 + n];
    float d = expf(logd[0]);
    Q[n] = d * (Bv[n] + 0.5f * s);
    P[n] = Cv[n];
}

// ---------------- K[a*128+b] = dot(P[a], Q[b]) ----------------
__global__ __launch_bounds__(256) void k_kdot(const float* __restrict__ P,
                                              const float* __restrict__ Q,
                                              float* __restrict__ K) {
    int t = threadIdx.x;
    int wid = blockIdx.x * 4 + (t >> 6), lane = t & 63;
    int a = wid >> 7, b = wid & 127;
    const float* Pr = P + (size_t)a * N1;
    const float* Qr = Q + (size_t)b * N1;
    float acc = 0.f;
#pragma unroll
    for (int jj = 0; jj < 4; ++jj) {
        int m = jj * 256 + lane * 4;
        float4 p = *(const float4*)&Pr[m];
        float4 q = *(const float4*)&Qr[m];
        acc += p.x * q.x + p.y * q.y + p.z * q.z + p.w * q.w;
    }
#pragma unroll
    for (int off = 32; off > 0; off >>= 1) acc += __shfl_down(acc, off, 64);
    if (lane == 0) K[wid] = acc;
}

// ---------------- conv phase 1 ----------------
__global__ __launch_bounds__(256) void k_conv1(const float* __restrict__ X,
                                               const float* __restrict__ K,
                                               float* __restrict__ part) {
    __shared__ __align__(16) float ks[1280];
    __shared__ __align__(16) float xs[256];
    int bx = blockIdx.x, tt = threadIdx.x;
    int o = 0;
    while (bx >= 2 * (o + 1) * (o + 1) + 2 * (o + 1)) ++o;
    int jt = bx - (2 * o * o + 2 * o);
    int T0 = o * 1024, J0 = jt * 256;
    int mb = T0 - J0 - 255;
    for (int ii = tt; ii < 1280; ii += 256) {
        int m = mb + ii;
        ks[ii] = (m >= 0 && m < LL) ? K[m] : 0.f;
    }
    xs[tt] = X[J0 + tt];
    __syncthreads();

    float acc0 = 0.f, acc1 = 0.f, acc2 = 0.f, acc3 = 0.f;
    int base0 = 4 * tt + 252;
#pragma unroll 4
    for (int jj = 0; jj < 256; jj += 4) {
        float4 xv  = *(const float4*)&xs[jj];
        float4 kv0 = *(const float4*)&ks[base0 - jj];
        float4 kv1 = *(const float4*)&ks[base0 - jj + 4];
        float kk0 = kv0.x, kk1 = kv0.y, kk2 = kv0.z, kk3 = kv0.w;
        float kk4 = kv1.x, kk5 = kv1.y, kk6 = kv1.z;
        acc0 += kk3 * xv.x + kk2 * xv.y + kk1 * xv.z + kk0 * xv.w;
        acc1 += kk4 * xv.x + kk3 * xv.y + kk2 * xv.z + kk1 * xv.w;
        acc2 += kk5 * xv.x + kk4 * xv.y + kk3 * xv.z + kk2 * xv.w;
        acc3 += kk6 * xv.x + kk5 * xv.y + kk4 * xv.z + kk3 * xv.w;
    }
    float4 out = {acc0, acc1, acc2, acc3};
    *(float4*)&part[((size_t)(o * 64 + jt)) * 1024 + 4 * tt] = out;
}

// ---------------- conv phase 2 ----------------
__global__ __launch_bounds__(256) void k_conv2(const float* __restrict__ X,
                                               const float* __restrict__ part,
                                               const float* __restrict__ Dp,
                                               float* __restrict__ Y) {
    int o = blockIdx.x, tt = threadIdx.x;
    int c = 4 * tt;
    float s0 = 0.f, s1 = 0.f, s2 = 0.f, s3 = 0.f;
    int cnt = 4 * o + 4;
    for (int jt = 0; jt < cnt; ++jt) {
        float4 p = *(const float4*)&part[((size_t)(o * 64 + jt)) * 1024 + c];
        s0 += p.x; s1 += p.y; s2 += p.z; s3 += p.w;
    }
    float dsk = Dp[0];
    int t = o * 1024 + c;
    float4 xv = *(const float4*)&X[t];
    float4 out;
    out.x = dsk * xv.x + s0;
    out.y = dsk * xv.y + s1;
    out.z = dsk * xv.z + s2;
    out.w = dsk * xv.w + s3;
    *(float4*)&Y[t] = out;
}

extern "C" void kernel_launch(void* const* d_in, const int* in_sizes, int n_in,
                              void* d_out, int out_size, void* d_ws, size_t ws_size,
                              hipStream_t stream) {
    const float* X    = (const float*)d_in[0];
    const float* A    = (const float*)d_in[1];
    const float* Bv   = (const float*)d_in[2];
    const float* Cv   = (const float*)d_in[3];
    const float* Dp   = (const float*)d_in[4];
    const float* logd = (const float*)d_in[5];
    float* ws = (float*)d_ws;

    float* S0 = ws;                 // e, squaring ping-pong
    float* S1 = ws + (size_t)NN2;   // e2
    float* S2 = ws + 2*(size_t)NN2; // e^2+e^4
    float* S3 = ws + 3*(size_t)NN2; // e+e^2
    float* S4 = ws + 4*(size_t)NN2; // D1, squaring ping-pong
    float* MP = ws + 5*(size_t)NN2; // mm partials (4 x NN2); also conv partials
    float* CP = ws + 9*(size_t)NN2; // chain partials (<=64 KB)
    float* Q  = CP + 64*(size_t)N1;         // 128 x 1024
    float* P  = Q + 128*(size_t)N1;         // 128 x 1024
    float* Kc = P + 128*(size_t)N1;         // 16384
    float* Y  = (float*)d_out;

    k_scale<<<4096, 256, 0, stream>>>(A, logd, S0);      // e = (d/2)A
    // build D1 = 2e(I+e)(I+e^2+e^4)
    k_fused<<<256, 256, 0, stream>>>(S0, S0, MP, nullptr, nullptr, 0, 0, 0, 0);
    k_redu<<<1024, 256, 0, stream>>>(MP, S0, S1, 1.f, 0.f, nullptr, nullptr, 0, 0);
    k_fused<<<256, 256, 0, stream>>>(S1, S1, MP, nullptr, nullptr, 0, 0, 0, 0);
    k_redu<<<1024, 256, 0, stream>>>(MP, S1, S2, 1.f, 1.f, nullptr, nullptr, 0, 0);
    k_add<<<4096, 256, 0, stream>>>(S0, S1, S3);
    k_fused<<<256, 256, 0, stream>>>(S3, S2, MP, nullptr, nullptr, 0, 0, 0, 0);
    k_redu<<<1024, 256, 0, stream>>>(MP, S3, S4, 2.f, 2.f, nullptr, nullptr, 0, 0);

    // init: Q[0] = d*(B + 0.5*D1@B); P[0] = C
    k_cpart<<<256, 256, 0, stream>>>(S4, (float*)Bv, CP, 1, 4, 0);
    k_initR<<<4, 256, 0, stream>>>(Bv, Cv, logd, CP, Q, P);

    float* cur = S4;
    float* nxt = S0;
    // Q loop: chain step w=2^k with D_{2^k}, fused with squaring -> D_{2^{k+1}}
    for (int k = 0; k < 7; ++k) {
        int w = 1 << k;
        int lkc = (w < 16) ? (4 - k) : 0;
        int kc = 1 << lkc;
        int nchain = 16 * kc * w;
        int nR = (kc > 1) ? 4 * w : 0;
        k_fused<<<nchain + 256, 256, 0, stream>>>(cur, cur, MP, Q, CP, w, lkc, nchain, 0);
        k_redu<<<1024 + nR, 256, 0, stream>>>(MP, cur, nxt, 1.f, 2.f, Q, CP, w, kc);
        float* tsw = cur; cur = nxt; nxt = tsw;
    }
    // P loop: k=0..5 fused with squarings
    for (int k = 0; k < 6; ++k) {
        int w = 1 << k;
        int lkc = (w < 16) ? (4 - k) : 0;
        int kc = 1 << lkc;
        int nchain = 16 * kc * w;
        int nR = (kc > 1) ? 4 * w : 0;
        k_fused<<<nchain + 256, 256, 0, stream>>>(cur, cur, MP, P, CP, w, lkc, nchain, 1);
        k_redu<<<1024 + nR, 256, 0, stream>>>(MP, cur, nxt, 1.f, 2.f, P, CP, w, kc);
        float* tsw = cur; cur = nxt; nxt = tsw;
    }
    // final P step: w=64 with D_8192, direct write
    k_cpart<<<1024, 256, 0, stream>>>(cur, P, CP, 64, 0, 1);

    k_kdot<<<4096, 256, 0, stream>>>(P, Q, Kc);
    k_conv1<<<544, 256, 0, stream>>>(X, Kc, MP);
    k_conv2<<<16, 256, 0, stream>>>(X, MP, Dp, Y);
}

// Round 6
// 1005.475 us; speedup vs baseline: 2.8007x; 2.8007x over previous
//
#include <hip/hip_runtime.h>
#include <math.h>

#define N1 1024
#define NN2 (N1*N1)
#define LL 16384

// ---------------- elementwise ----------------
__global__ __launch_bounds__(256) void k_scale(const float* __restrict__ A,
                                               const float* __restrict__ logd,
                                               float* __restrict__ e) {
    int i = blockIdx.x * 256 + threadIdx.x;
    float d = expf(logd[0]);
    e[i] = 0.5f * d * A[i];
}

__global__ __launch_bounds__(256) void k_add(const float* __restrict__ a,
                                             const float* __restrict__ b,
                                             float* __restrict__ o) {
    int i = blockIdx.x * 256 + threadIdx.x;
    o[i] = a[i] + b[i];
}

// ---------------- chain-partial device code (mode 0 = Q rows, 1 = P cols) --------
__device__ __forceinline__ void chain_part(const float* __restrict__ M,
                                           float* __restrict__ V,
                                           float* __restrict__ CP,
                                           int w, int lkc, int mode, int cb,
                                           float* sV, float (*red)[64]) {
    int kc = 1 << lkc;
    int i = cb >> (4 + lkc);
    int ky = (cb >> 4) & (kc - 1);
    int nx = cb & 15;
    int mlen = N1 >> lkc;
    int m0 = ky * mlen, n0 = nx * 64;
    int t = threadIdx.x;
    const float* Vi = V + (size_t)i * N1 + m0;
    if (t * 4 < mlen) *(float4*)&sV[t * 4] = *(const float4*)&Vi[t * 4];
    __syncthreads();
    int wave = t >> 6, lane = t & 63;
    if (mode == 0) {
        for (int rr = 0; rr < 16; ++rr) {
            int n = n0 + wave * 16 + rr;
            const float* Mr = M + (size_t)n * N1 + m0;
            float acc = 0.f;
            for (int m = lane * 4; m < mlen; m += 256) {
                float4 a = *(const float4*)&Mr[m];
                float4 v = *(const float4*)&sV[m];
                acc += a.x * v.x + a.y * v.y + a.z * v.z + a.w * v.w;
            }
#pragma unroll
            for (int off = 32; off > 0; off >>= 1) acc += __shfl_down(acc, off, 64);
            if (lane == 0) {
                if (kc == 1) V[(size_t)(w + i) * N1 + n] = sV[n] + acc;
                else CP[((size_t)i * kc + ky) * N1 + n] = acc;
            }
        }
    } else {
        int n = n0 + lane;
        int msub = mlen >> 2;
        int mb = wave * msub;
        float acc = 0.f;
#pragma unroll 8
        for (int m = 0; m < msub; ++m)
            acc += sV[mb + m] * M[(size_t)(m0 + mb + m) * N1 + n];
        red[wave][lane] = acc;
        __syncthreads();
        if (t < 64) {
            float s = red[0][t] + red[1][t] + red[2][t] + red[3][t];
            if (kc == 1) V[(size_t)(w + i) * N1 + n0 + t] = sV[n0 + t] + s;
            else CP[((size_t)i * kc + ky) * N1 + n0 + t] = s;
        }
    }
}

// ---------------- fused dispatch: [chain blocks | 256 SGEMM split-K blocks] --------
// GEMM: part[z] = Ain[:, z*256:(z+1)*256] @ Bin[z*256:..., :]
// 128x128 tile, BK=16, 256 threads, 8x8/thread (split 4+4), double-buffered LDS.
// NOTE: no min-waves launch bound — (256,2) capped VGPR at 128 and spilled the
// 8x8 accumulator to scratch (R5: 378 MB WRITE_SIZE/dispatch, 3.5x regression).
__global__ __launch_bounds__(256, 1) void k_fused(const float* __restrict__ Ain,
                                                  const float* __restrict__ Bin,
                                                  float* __restrict__ part,
                                                  float* __restrict__ V,
                                                  float* __restrict__ CP,
                                                  int w, int lkc, int nchain, int mode) {
    __shared__ float As[2][16][136];
    __shared__ float Bs[2][16][136];
    __shared__ float sV[N1];
    __shared__ float red[4][64];
    int b = blockIdx.x;
    if (b < nchain) {
        chain_part(Ain, V, CP, w, lkc, mode, b, sV, red);
        return;
    }
    int g = b - nchain;
    int t = threadIdx.x;
    int z = g >> 6, ty = (g >> 3) & 7, tx = g & 7;
    int m0 = ty * 128, n0 = tx * 128, kz = z * 256;
    int tm = (t & 15) * 4, tn = (t >> 4) * 4;
    int arow = t >> 1, akb = (t & 1) * 8;
    int bkr = t >> 4, bnb = (t & 15) * 8;
    const float* Ap = Ain + (size_t)(m0 + arow) * N1 + kz + akb;
    const float* Bp = Bin + (size_t)(kz + bkr) * N1 + n0 + bnb;

    float4 pa0 = *(const float4*)(Ap);
    float4 pa1 = *(const float4*)(Ap + 4);
    float4 pb0 = *(const float4*)(Bp);
    float4 pb1 = *(const float4*)(Bp + 4);
    As[0][akb + 0][arow] = pa0.x; As[0][akb + 1][arow] = pa0.y;
    As[0][akb + 2][arow] = pa0.z; As[0][akb + 3][arow] = pa0.w;
    As[0][akb + 4][arow] = pa1.x; As[0][akb + 5][arow] = pa1.y;
    As[0][akb + 6][arow] = pa1.z; As[0][akb + 7][arow] = pa1.w;
    *(float4*)&Bs[0][bkr][bnb]     = pb0;
    *(float4*)&Bs[0][bkr][bnb + 4] = pb1;
    __syncthreads();

    float acc[8][8];
#pragma unroll
    for (int i = 0; i < 8; ++i)
#pragma unroll
        for (int j = 0; j < 8; ++j) acc[i][j] = 0.f;

    for (int tt_ = 0; tt_ < 16; ++tt_) {
        int cb = tt_ & 1;
        float4 na0, na1, nb0, nb1;
        if (tt_ < 15) {
            int k0 = (tt_ + 1) * 16;
            na0 = *(const float4*)(Ap + k0);
            na1 = *(const float4*)(Ap + k0 + 4);
            nb0 = *(const float4*)(Bp + (size_t)k0 * N1);
            nb1 = *(const float4*)(Bp + (size_t)k0 * N1 + 4);
        }
#pragma unroll
        for (int k = 0; k < 16; ++k) {
            float4 a0 = *(float4*)&As[cb][k][tm];
            float4 a1 = *(float4*)&As[cb][k][tm + 64];
            float4 b0 = *(float4*)&Bs[cb][k][tn];
            float4 b1 = *(float4*)&Bs[cb][k][tn + 64];
            float av[8] = {a0.x, a0.y, a0.z, a0.w, a1.x, a1.y, a1.z, a1.w};
            float bv[8] = {b0.x, b0.y, b0.z, b0.w, b1.x, b1.y, b1.z, b1.w};
#pragma unroll
            for (int i = 0; i < 8; ++i)
#pragma unroll
                for (int j = 0; j < 8; ++j) acc[i][j] += av[i] * bv[j];
        }
        if (tt_ < 15) {
            int nb_ = cb ^ 1;
            As[nb_][akb + 0][arow] = na0.x; As[nb_][akb + 1][arow] = na0.y;
            As[nb_][akb + 2][arow] = na0.z; As[nb_][akb + 3][arow] = na0.w;
            As[nb_][akb + 4][arow] = na1.x; As[nb_][akb + 5][arow] = na1.y;
            As[nb_][akb + 6][arow] = na1.z; As[nb_][akb + 7][arow] = na1.w;
            *(float4*)&Bs[nb_][bkr][bnb]     = nb0;
            *(float4*)&Bs[nb_][bkr][bnb + 4] = nb1;
            __syncthreads();
        }
    }
    float* Po = part + (size_t)z * NN2;
#pragma unroll
    for (int ih = 0; ih < 2; ++ih)
#pragma unroll
        for (int i = 0; i < 4; ++i) {
            int row = m0 + tm + ih * 64 + i;
            float4 o0 = {acc[ih * 4 + i][0], acc[ih * 4 + i][1], acc[ih * 4 + i][2], acc[ih * 4 + i][3]};
            float4 o1 = {acc[ih * 4 + i][4], acc[ih * 4 + i][5], acc[ih * 4 + i][6], acc[ih * 4 + i][7]};
            *(float4*)&Po[(size_t)row * N1 + n0 + tn] = o0;
            *(float4*)&Po[(size_t)row * N1 + n0 + tn + 64] = o1;
        }
}

// ---------------- chain-partial-only dispatch ----------------
__global__ __launch_bounds__(256) void k_cpart(const float* __restrict__ M,
                                               float* __restrict__ V,
                                               float* __restrict__ CP,
                                               int w, int lkc, int mode) {
    __shared__ float sV[N1];
    __shared__ float red[4][64];
    chain_part(M, V, CP, w, lkc, mode, blockIdx.x, sV, red);
}

// ---------------- fused reduce: [1024 mmred blocks | 4w chainR blocks] ------------
__global__ __launch_bounds__(256) void k_redu(const float* __restrict__ part,
                                              const float* __restrict__ Aadd,
                                              float* __restrict__ C,
                                              float alpha, float beta,
                                              float* __restrict__ V,
                                              const float* __restrict__ CP,
                                              int w, int kc) {
    int b = blockIdx.x, t = threadIdx.x;
    if (b < 1024) {
        int i = (b * 256 + t) * 4;
        float4 p0 = *(const float4*)&part[i];
        float4 p1 = *(const float4*)&part[NN2 + i];
        float4 p2 = *(const float4*)&part[2 * (size_t)NN2 + i];
        float4 p3 = *(const float4*)&part[3 * (size_t)NN2 + i];
        float4 av = *(const float4*)&Aadd[i];
        float4 o;
        o.x = alpha * ((p0.x + p1.x) + (p2.x + p3.x)) + beta * av.x;
        o.y = alpha * ((p0.y + p1.y) + (p2.y + p3.y)) + beta * av.y;
        o.z = alpha * ((p0.z + p1.z) + (p2.z + p3.z)) + beta * av.z;
        o.w = alpha * ((p0.w + p1.w) + (p2.w + p3.w)) + beta * av.w;
        *(float4*)&C[i] = o;
    } else {
        int rb = b - 1024;
        int i = rb >> 2;
        int n = (rb & 3) * 256 + t;
        const float* pp = CP + (size_t)i * kc * N1 + n;
        float s = 0.f;
        for (int c = 0; c < kc; ++c) s += pp[(size_t)c * N1];
        V[(size_t)(w + i) * N1 + n] = V[(size_t)i * N1 + n] + s;
    }
}

// ---------------- init reduce: Q[0] = d*(B + 0.5*D1@B); P[0] = C ----------------
__global__ __launch_bounds__(256) void k_initR(const float* __restrict__ Bv,
                                               const float* __restrict__ Cv,
                                               const float* __restrict__ logd,
                                               const float* __restrict__ part,
                                               float* __restrict__ Q,
                                               float* __restrict__ P) {
    int n = blockIdx.x * 256 + threadIdx.x;
    float s = 0.f;
    for (int c = 0; c < 16; ++c) s += part[(size_t)c * N1 + n];
    float d = expf(logd[0]);
    Q[n] = d * (Bv[n] + 0.5f * s);
    P[n] = Cv[n];
}

// ---------------- K[a*128+b] = dot(P[a], Q[b]) ----------------
__global__ __launch_bounds__(256) void k_kdot(const float* __restrict__ P,
                                              const float* __restrict__ Q,
                                              float* __restrict__ K) {
    int t = threadIdx.x;
    int wid = blockIdx.x * 4 + (t >> 6), lane = t & 63;
    int a = wid >> 7, b = wid & 127;
    const float* Pr = P + (size_t)a * N1;
    const float* Qr = Q + (size_t)b * N1;
    float acc = 0.f;
#pragma unroll
    for (int jj = 0; jj < 4; ++jj) {
        int m = jj * 256 + lane * 4;
        float4 p = *(const float4*)&Pr[m];
        float4 q = *(const float4*)&Qr[m];
        acc += p.x * q.x + p.y * q.y + p.z * q.z + p.w * q.w;
    }
#pragma unroll
    for (int off = 32; off > 0; off >>= 1) acc += __shfl_down(acc, off, 64);
    if (lane == 0) K[wid] = acc;
}

// ---------------- conv phase 1 ----------------
__global__ __launch_bounds__(256) void k_conv1(const float* __restrict__ X,
                                               const float* __restrict__ K,
                                               float* __restrict__ part) {
    __shared__ __align__(16) float ks[1280];
    __shared__ __align__(16) float xs[256];
    int bx = blockIdx.x, tt = threadIdx.x;
    int o = 0;
    while (bx >= 2 * (o + 1) * (o + 1) + 2 * (o + 1)) ++o;
    int jt = bx - (2 * o * o + 2 * o);
    int T0 = o * 1024, J0 = jt * 256;
    int mb = T0 - J0 - 255;
    for (int ii = tt; ii < 1280; ii += 256) {
        int m = mb + ii;
        ks[ii] = (m >= 0 && m < LL) ? K[m] : 0.f;
    }
    xs[tt] = X[J0 + tt];
    __syncthreads();

    float acc0 = 0.f, acc1 = 0.f, acc2 = 0.f, acc3 = 0.f;
    int base0 = 4 * tt + 252;
#pragma unroll 4
    for (int jj = 0; jj < 256; jj += 4) {
        float4 xv  = *(const float4*)&xs[jj];
        float4 kv0 = *(const float4*)&ks[base0 - jj];
        float4 kv1 = *(const float4*)&ks[base0 - jj + 4];
        float kk0 = kv0.x, kk1 = kv0.y, kk2 = kv0.z, kk3 = kv0.w;
        float kk4 = kv1.x, kk5 = kv1.y, kk6 = kv1.z;
        acc0 += kk3 * xv.x + kk2 * xv.y + kk1 * xv.z + kk0 * xv.w;
        acc1 += kk4 * xv.x + kk3 * xv.y + kk2 * xv.z + kk1 * xv.w;
        acc2 += kk5 * xv.x + kk4 * xv.y + kk3 * xv.z + kk2 * xv.w;
        acc3 += kk6 * xv.x + kk5 * xv.y + kk4 * xv.z + kk3 * xv.w;
    }
    float4 out = {acc0, acc1, acc2, acc3};
    *(float4*)&part[((size_t)(o * 64 + jt)) * 1024 + 4 * tt] = out;
}

// ---------------- conv phase 2 ----------------
__global__ __launch_bounds__(256) void k_conv2(const float* __restrict__ X,
                                               const float* __restrict__ part,
                                               const float* __restrict__ Dp,
                                               float* __restrict__ Y) {
    int o = blockIdx.x, tt = threadIdx.x;
    int c = 4 * tt;
    float s0 = 0.f, s1 = 0.f, s2 = 0.f, s3 = 0.f;
    int cnt = 4 * o + 4;
    for (int jt = 0; jt < cnt; ++jt) {
        float4 p = *(const float4*)&part[((size_t)(o * 64 + jt)) * 1024 + c];
        s0 += p.x; s1 += p.y; s2 += p.z; s3 += p.w;
    }
    float dsk = Dp[0];
    int t = o * 1024 + c;
    float4 xv = *(const float4*)&X[t];
    float4 out;
    out.x = dsk * xv.x + s0;
    out.y = dsk * xv.y + s1;
    out.z = dsk * xv.z + s2;
    out.w = dsk * xv.w + s3;
    *(float4*)&Y[t] = out;
}

extern "C" void kernel_launch(void* const* d_in, const int* in_sizes, int n_in,
                              void* d_out, int out_size, void* d_ws, size_t ws_size,
                              hipStream_t stream) {
    const float* X    = (const float*)d_in[0];
    const float* A    = (const float*)d_in[1];
    const float* Bv   = (const float*)d_in[2];
    const float* Cv   = (const float*)d_in[3];
    const float* Dp   = (const float*)d_in[4];
    const float* logd = (const float*)d_in[5];
    float* ws = (float*)d_ws;

    float* S0 = ws;                 // e, squaring ping-pong
    float* S1 = ws + (size_t)NN2;   // e2
    float* S2 = ws + 2*(size_t)NN2; // e^2+e^4
    float* S3 = ws + 3*(size_t)NN2; // e+e^2
    float* S4 = ws + 4*(size_t)NN2; // D1, squaring ping-pong
    float* MP = ws + 5*(size_t)NN2; // mm partials (4 x NN2); also conv partials
    float* CP = ws + 9*(size_t)NN2; // chain partials (<=64 KB)
    float* Q  = CP + 64*(size_t)N1;         // 128 x 1024
    float* P  = Q + 128*(size_t)N1;         // 128 x 1024
    float* Kc = P + 128*(size_t)N1;         // 16384
    float* Y  = (float*)d_out;

    k_scale<<<4096, 256, 0, stream>>>(A, logd, S0);      // e = (d/2)A
    // build D1 = 2e(I+e)(I+e^2+e^4)
    k_fused<<<256, 256, 0, stream>>>(S0, S0, MP, nullptr, nullptr, 0, 0, 0, 0);
    k_redu<<<1024, 256, 0, stream>>>(MP, S0, S1, 1.f, 0.f, nullptr, nullptr, 0, 0);
    k_fused<<<256, 256, 0, stream>>>(S1, S1, MP, nullptr, nullptr, 0, 0, 0, 0);
    k_redu<<<1024, 256, 0, stream>>>(MP, S1, S2, 1.f, 1.f, nullptr, nullptr, 0, 0);
    k_add<<<4096, 256, 0, stream>>>(S0, S1, S3);
    k_fused<<<256, 256, 0, stream>>>(S3, S2, MP, nullptr, nullptr, 0, 0, 0, 0);
    k_redu<<<1024, 256, 0, stream>>>(MP, S3, S4, 2.f, 2.f, nullptr, nullptr, 0, 0);

    // init: Q[0] = d*(B + 0.5*D1@B); P[0] = C
    k_cpart<<<256, 256, 0, stream>>>(S4, (float*)Bv, CP, 1, 4, 0);
    k_initR<<<4, 256, 0, stream>>>(Bv, Cv, logd, CP, Q, P);

    float* cur = S4;
    float* nxt = S0;
    // Q loop: chain step w=2^k with D_{2^k}, fused with squaring -> D_{2^{k+1}}
    for (int k = 0; k < 7; ++k) {
        int w = 1 << k;
        int lkc = (w < 16) ? (4 - k) : 0;
        int kc = 1 << lkc;
        int nchain = 16 * kc * w;
        int nR = (kc > 1) ? 4 * w : 0;
        k_fused<<<nchain + 256, 256, 0, stream>>>(cur, cur, MP, Q, CP, w, lkc, nchain, 0);
        k_redu<<<1024 + nR, 256, 0, stream>>>(MP, cur, nxt, 1.f, 2.f, Q, CP, w, kc);
        float* tsw = cur; cur = nxt; nxt = tsw;
    }
    // P loop: k=0..5 fused with squarings
    for (int k = 0; k < 6; ++k) {
        int w = 1 << k;
        int lkc = (w < 16) ? (4 - k) : 0;
        int kc = 1 << lkc;
        int nchain = 16 * kc * w;
        int nR = (kc > 1) ? 4 * w : 0;
        k_fused<<<nchain + 256, 256, 0, stream>>>(cur, cur, MP, P, CP, w, lkc, nchain, 1);
        k_redu<<<1024 + nR, 256, 0, stream>>>(MP, cur, nxt, 1.f, 2.f, P, CP, w, kc);
        float* tsw = cur; cur = nxt; nxt = tsw;
    }
    // final P step: w=64 with D_8192, direct write
    k_cpart<<<1024, 256, 0, stream>>>(cur, P, CP, 64, 0, 1);

    k_kdot<<<4096, 256, 0, stream>>>(P, Q, Kc);
    k_conv1<<<544, 256, 0, stream>>>(X, Kc, MP);
    k_conv2<<<16, 256, 0, stream>>>(X, MP, Dp, Y);
}